// Round 1
// 243.071 us; speedup vs baseline: 1.0976x; 1.0976x over previous
//
#include <hip/hip_runtime.h>
#include <hip/hip_fp16.h>
#include <cstdint>

typedef unsigned short ushort_t;
typedef _Float16 f16x8 __attribute__((ext_vector_type(8)));  // 8 f16 (4 VGPRs) for MFMA
typedef float f32x4 __attribute__((ext_vector_type(4)));
typedef unsigned int u32x4 __attribute__((ext_vector_type(4)));

#define M_TOT  32768
#define K_EMB  256
#define K_CORE 512
#define ACT    12

__device__ __forceinline__ unsigned int pack2h(float a, float b) {
    __half2 h = __floats2half2_rn(a, b);
    union { __half2 h2; unsigned int u; } v; v.h2 = h; return v.u;
}

// ---------- kernel 1: transpose+convert W1[0:256, 0:1024] f32 -> W1T f16 [1024][256] ----------
__global__ __launch_bounds__(256) void transpose_k(const float* __restrict__ W1,
                                                   ushort_t* __restrict__ W1T) {
    __shared__ float tile[64][65];
    const int t = threadIdx.x;
    const int k0 = blockIdx.x * 64, n0 = blockIdx.y * 64;
    const int r = t >> 4, c4 = (t & 15) * 4;
#pragma unroll
    for (int p = 0; p < 4; ++p) {
        const int row = r + p * 16;
        const float4 v = *(const float4*)(W1 + (size_t)(k0 + row) * 1024 + n0 + c4);
        tile[row][c4 + 0] = v.x; tile[row][c4 + 1] = v.y;
        tile[row][c4 + 2] = v.z; tile[row][c4 + 3] = v.w;
    }
    __syncthreads();
#pragma unroll
    for (int p = 0; p < 4; ++p) {
        const int nrow = r + p * 16;
        uint2 o;
        o.x = pack2h(tile[c4 + 0][nrow], tile[c4 + 1][nrow]);
        o.y = pack2h(tile[c4 + 2][nrow], tile[c4 + 3][nrow]);
        *(uint2*)(W1T + (size_t)(n0 + nrow) * 256 + k0 + c4) = o;
    }
}

// ---------- kernel 2: cp[b][n] = b1[n] + sum_k core[b][k] * W1[256+k][n]  (exact f32) ----------
__global__ __launch_bounds__(256) void corepart_k(const float* __restrict__ core,
                                                  const float* __restrict__ W1,
                                                  const float* __restrict__ b1,
                                                  float* __restrict__ cp) {
    const int b = blockIdx.y;
    const int n = blockIdx.x * 256 + threadIdx.x;
    const float* cr = core + b * K_CORE;
    const float* wp = W1 + (size_t)K_EMB * 1024 + n;
    float s0 = 0.f, s1 = 0.f, s2 = 0.f, s3 = 0.f;
#pragma unroll 4
    for (int k = 0; k < K_CORE; k += 4) {
        s0 += cr[k + 0] * wp[(size_t)(k + 0) * 1024];
        s1 += cr[k + 1] * wp[(size_t)(k + 1) * 1024];
        s2 += cr[k + 2] * wp[(size_t)(k + 2) * 1024];
        s3 += cr[k + 3] * wp[(size_t)(k + 3) * 1024];
    }
    cp[b * 1024 + n] = b1[n] + ((s0 + s1) + (s2 + s3));
}

// ---------- kernel 3 (fused): BM=64 rows/block, 512 blocks (2/CU).
// A-tile (64x256 f16, XOR-swizzled) resident in LDS for the whole block -> emb read ONCE.
// B-tile (128x32 f16) double-buffered -> 1 barrier/iter.
// MFMA operands SWAPPED: D col=lane16=m, row=qd*4+r=n  -> float4 out1 stores,
// float4 cp loads, and logit partials shrink 192->48 VGPRs.
__global__ __launch_bounds__(256, 2) void fused_k(const float* __restrict__ emb,
                                                  const ushort_t* __restrict__ w1t,
                                                  const float* __restrict__ cp,
                                                  const float* __restrict__ W2,
                                                  const float* __restrict__ b2,
                                                  const int* __restrict__ nr_units,
                                                  const int* __restrict__ nr_flags,
                                                  float* __restrict__ out0,
                                                  float* __restrict__ out1) {
    __shared__ __align__(16) ushort_t Asl[64 * 256];       // 32 KB, row stride 512B, swizzle g^=(r&7)
    __shared__ __align__(16) ushort_t Bsl[2][128 * 32];    // 2 x 8 KB, row stride 64B, swizzle g^=(r>>1)&3
    __shared__ __align__(16) float logitAcc[4][64][ACT];   // 12 KB

    const int t = threadIdx.x;
    const int w = t >> 6, L = t & 63;
    const int lane16 = L & 15, qd = L >> 4;
    const int m0 = blockIdx.x * 64;
    const int bb = blockIdx.x >> 3;

    // ---- stage FULL A tile: 64 rows x 256 k, f32 -> f16, XOR-swizzled (once per block) ----
    {
        const int g = t & 31;          // 8-f16 group within row (0..31)
        const int rsub = t >> 5;       // 0..7
#pragma unroll
        for (int p = 0; p < 8; ++p) {
            const int r = p * 8 + rsub;
            const float* src = emb + (size_t)(m0 + r) * K_EMB + g * 8;
            const f32x4 v0 = __builtin_nontemporal_load((const f32x4*)src);
            const f32x4 v1 = __builtin_nontemporal_load((const f32x4*)src + 1);
            u32x4 pk;
            pk[0] = pack2h(v0[0], v0[1]); pk[1] = pack2h(v0[2], v0[3]);
            pk[2] = pack2h(v1[0], v1[1]); pk[3] = pack2h(v1[2], v1[3]);
            *(u32x4*)((char*)Asl + r * 512 + ((g ^ (r & 7)) << 4)) = pk;
        }
    }

    // ---- B staging geometry: 256 threads x 2 chunks of 8 f16 ----
    const int rB = t >> 2, gB = t & 3;
    const ushort_t* gBa = w1t + (size_t)rB * K_EMB + gB * 8;   // rows 0..63 of current B tile
    const int wb0 = rB * 64 + ((gB ^ ((rB >> 1) & 3)) << 4);
    const int wb1 = wb0 + 64 * 64;                             // row+64: same XOR bits

    // initial B tile (it=0: nt=0, ks=0) -> buffer 0
    {
        const u32x4 b0 = *(const u32x4*)gBa;
        const u32x4 b1v = *(const u32x4*)(gBa + 64 * K_EMB);
        *(u32x4*)((char*)Bsl + wb0) = b0;
        *(u32x4*)((char*)Bsl + wb1) = b1v;
    }
    __syncthreads();   // A tile + B0 visible

    // ---- fragment read bases ----
    const int araw = lane16 * 512;         // + mi*8192 + per-iter XOR'd group
    const int axor = lane16 & 7;
    const int bswz = (qd ^ ((lane16 >> 1) & 3)) << 4;
    int boffc[2];
#pragma unroll
    for (int ni = 0; ni < 2; ++ni)
        boffc[ni] = (w * 32 + ni * 16 + lane16) * 64 + bswz;

    // ---- accumulators ----
    f32x4 acc[2][4];                       // [ni][mi]: D rows=n (qd*4+r), cols=m (lane16)
#pragma unroll
    for (int ni = 0; ni < 2; ++ni)
#pragma unroll
        for (int mi = 0; mi < 4; ++mi) acc[ni][mi] = (f32x4){0.f, 0.f, 0.f, 0.f};
    f32x4 la[4][3];                        // logit partials: per lane, 4 m-rows x 12 acts
#pragma unroll
    for (int mi = 0; mi < 4; ++mi)
#pragma unroll
        for (int c = 0; c < 3; ++c) la[mi][c] = (f32x4){0.f, 0.f, 0.f, 0.f};

    u32x4 pb0, pb1;
    int cur = 0;
    for (int it = 0; it < 64; ++it) {
        const int ks = it & 7;
        if (it < 63) {                     // prefetch next B tile into regs (latency hides under MFMA)
            const int itn = it + 1;
            const size_t off = (size_t)(itn >> 3) * 128 * K_EMB + (size_t)(itn & 7) * 32;
            pb0 = *(const u32x4*)(gBa + off);
            pb1 = *(const u32x4*)(gBa + 64 * K_EMB + off);
        }
        // fragments
        const int ga = (((ks << 2) | qd) ^ axor) << 4;
        f16x8 af[4], bf[2];
#pragma unroll
        for (int mi = 0; mi < 4; ++mi)
            af[mi] = *(const f16x8*)((const char*)Asl + mi * 8192 + araw + ga);
        const char* bbase = (const char*)Bsl + cur * 8192;
#pragma unroll
        for (int ni = 0; ni < 2; ++ni)
            bf[ni] = *(const f16x8*)(bbase + boffc[ni]);
#pragma unroll
        for (int ni = 0; ni < 2; ++ni)
#pragma unroll
            for (int mi = 0; mi < 4; ++mi)
                acc[ni][mi] = __builtin_amdgcn_mfma_f32_16x16x32_f16(bf[ni], af[mi], acc[ni][mi], 0, 0, 0);

        if ((it & 7) == 7) {
            // ---- per-n-tile epilogue: +cp, relu, float4 store h, logit partials ----
            const int nt = it >> 3;
#pragma unroll
            for (int ni = 0; ni < 2; ++ni) {
                const int nbase = nt * 128 + w * 32 + ni * 16 + qd * 4;
                const f32x4 cpv = *(const f32x4*)(cp + bb * 1024 + nbase);
#pragma unroll
                for (int mi = 0; mi < 4; ++mi) {
                    f32x4 v = acc[ni][mi] + cpv;
#pragma unroll
                    for (int j = 0; j < 4; ++j) v[j] = v[j] > 0.f ? v[j] : 0.f;
                    acc[ni][mi] = v;
                    const size_t m = (size_t)(m0 + mi * 16 + lane16);
                    __builtin_nontemporal_store(v, (f32x4*)(out1 + m * 1024 + nbase));
                }
#pragma unroll
                for (int r = 0; r < 4; ++r) {
                    const f32x4* wp = (const f32x4*)(W2 + (size_t)(nbase + r) * ACT);
                    const f32x4 w2a = wp[0], w2b = wp[1], w2c = wp[2];
#pragma unroll
                    for (int mi = 0; mi < 4; ++mi) {
                        const float vv = acc[ni][mi][r];
                        la[mi][0] += w2a * vv;
                        la[mi][1] += w2b * vv;
                        la[mi][2] += w2c * vv;
                    }
                }
#pragma unroll
                for (int mi = 0; mi < 4; ++mi) acc[ni][mi] = (f32x4){0.f, 0.f, 0.f, 0.f};
            }
        }

        if (it < 63) {                     // write prefetched B into the other buffer
            char* bnxt = (char*)Bsl + ((cur ^ 1) * 8192);
            *(u32x4*)(bnxt + wb0) = pb0;
            *(u32x4*)(bnxt + wb1) = pb1;
        }
        __syncthreads();
        cur ^= 1;
    }

    // ---- reduce logit partials across qd (lanes l, l^16, l^32, l^48 share lane16) ----
#pragma unroll
    for (int mi = 0; mi < 4; ++mi)
#pragma unroll
        for (int c = 0; c < 3; ++c)
#pragma unroll
            for (int j = 0; j < 4; ++j) {
                la[mi][c][j] += __shfl_xor(la[mi][c][j], 16, 64);
                la[mi][c][j] += __shfl_xor(la[mi][c][j], 32, 64);
            }
    if (L < 16) {
#pragma unroll
        for (int mi = 0; mi < 4; ++mi) {
            f32x4* p = (f32x4*)&logitAcc[w][mi * 16 + L][0];
            p[0] = la[mi][0]; p[1] = la[mi][1]; p[2] = la[mi][2];
        }
    }
    __syncthreads();

    // ---- softmax + range mask, one thread per row ----
    if (t < 64) {
        float lg[ACT];
#pragma unroll
        for (int a = 0; a < ACT; ++a)
            lg[a] = logitAcc[0][t][a] + logitAcc[1][t][a]
                  + logitAcc[2][t][a] + logitAcc[3][t][a] + b2[a];
        float mx = lg[0];
#pragma unroll
        for (int a = 1; a < ACT; ++a) mx = fmaxf(mx, lg[a]);
        float s = 0.f;
#pragma unroll
        for (int a = 0; a < ACT; ++a) { lg[a] = __expf(lg[a] - mx); s += lg[a]; }
        const float inv = 1.f / s;
        const int m = m0 + t;
        const int u = m & 511;
        const float msk = (u >= nr_flags[bb] && u < nr_units[bb]) ? 1.0f : 1e-9f;
        f32x4 o0, o1, o2;
#pragma unroll
        for (int j = 0; j < 4; ++j) {
            o0[j] = lg[j] * inv * msk;
            o1[j] = lg[j + 4] * inv * msk;
            o2[j] = lg[j + 8] * inv * msk;
        }
        f32x4* op = (f32x4*)(out0 + (size_t)m * ACT);
        __builtin_nontemporal_store(o0, op + 0);
        __builtin_nontemporal_store(o1, op + 1);
        __builtin_nontemporal_store(o2, op + 2);
    }
}

extern "C" void kernel_launch(void* const* d_in, const int* in_sizes, int n_in,
                              void* d_out, int out_size, void* d_ws, size_t ws_size,
                              hipStream_t stream) {
    const float* core   = (const float*)d_in[0];
    const float* emb    = (const float*)d_in[1];
    const int* nr_units = (const int*)d_in[2];
    const int* nr_flags = (const int*)d_in[3];
    const float* W1     = (const float*)d_in[4];
    const float* b1     = (const float*)d_in[5];
    const float* W2     = (const float*)d_in[6];
    const float* b2     = (const float*)d_in[7];

    float* out0 = (float*)d_out;                       // probs [32768*12] f32
    float* out1 = out0 + (size_t)M_TOT * ACT;          // embedding [32768*1024] f32

    ushort_t* w1t = (ushort_t*)d_ws;                   // f16 [1024][256] = 512 KB
    float* cp = (float*)((char*)d_ws + (size_t)1024 * 256 * 2); // [64][1024] f32

    transpose_k<<<dim3(4, 16), 256, 0, stream>>>(W1, w1t);
    corepart_k<<<dim3(4, 64), 256, 0, stream>>>(core, W1, b1, cp);
    fused_k<<<dim3(512), 256, 0, stream>>>(emb, w1t, cp, W2, b2, nr_units, nr_flags, out0, out1);
}